// Round 10
// baseline (209.529 us; speedup 1.0000x reference)
//
#include <hip/hip_runtime.h>
#include <hip/hip_fp16.h>

// GCN 2-layer, r5 baseline + dimension-split gather1 (two passes).
// r7/r8 attribution: g1 = 41us, latency-bound; h1 (6.4MB) > 4MB L2/XCD ->
// ~37% of row reads pay L3 latency. Fix: h1 split into h1a/h1b (3.2MB each,
// L2-fits per XCD); gather1 runs as two LAUNCHES (global barrier = phase-proof
// L2 residency). Pass A: x[0:16] + partial W2 contribution (fp32, nt-stored).
// Pass B: x[16:32] + partial -> h2 fp16. ReLU elementwise, W2 row-split: exact.
// (r9 fix: nontemporal builtins need clang ext_vector, not HIP float4.)

#define NB   391      // buckets = ceil(100000/256); bucket = id >> 8
#define CAPB 5504     // padded per-bucket edge capacity (avg 4092, +22 sigma)
#define EPB  4096     // edges per partition block (4/thread at 1024 threads)

typedef float f32x4 __attribute__((ext_vector_type(4)));

__device__ __forceinline__ long nt_load_i64(const long* p) {
    return __builtin_nontemporal_load(p);
}

// --- pass 1: partition edges by dst-bucket; LDS-staged, coalesced run writes ---
__global__ __launch_bounds__(1024) void partition_kernel(
        const int* __restrict__ src, const int* __restrict__ dst,
        const float* __restrict__ ew,
        int* __restrict__ g_cur_d, int* __restrict__ g_cur_s,
        int2* __restrict__ pack_part, unsigned char* __restrict__ src_part, int m) {
    __shared__ int hist_d[NB], hist_s[NB];
    __shared__ int lbase_d[NB], lbase_s[NB];
    __shared__ int gbase_d[NB], gbase_s[NB];
    __shared__ int cur_d[NB], cur_s[NB];
    __shared__ int woffd[16], woffs[16];
    __shared__ long stage[EPB];            // 32 KB
    __shared__ unsigned short dbuck[EPB];  // 8 KB
    __shared__ unsigned char  sstage[EPB]; // 4 KB
    __shared__ unsigned short sbuck[EPB];  // 8 KB
    int t = threadIdx.x, lane = t & 63, w = t >> 6;
    for (int i = t; i < NB; i += 1024) {
        hist_d[i] = 0; hist_s[i] = 0; cur_d[i] = 0; cur_s[i] = 0;
    }
    __syncthreads();
    int base_e = blockIdx.x * EPB;
    int total = m - base_e; if (total > EPB) total = EPB;
    int es[4], ed[4]; float wv[4];
#pragma unroll
    for (int k = 0; k < 4; k++) {
        int e = base_e + k * 1024 + t;
        if (e < m) { es[k] = src[e]; ed[k] = dst[e]; wv[k] = ew[e]; }
        else ed[k] = -1;
    }
#pragma unroll
    for (int k = 0; k < 4; k++) {
        if (ed[k] >= 0) {
            atomicAdd(&hist_d[ed[k] >> 8], 1);
            atomicAdd(&hist_s[es[k] >> 8], 1);
        }
    }
    __syncthreads();
    // fused exclusive scans of hist_d/hist_s (NB=391) via wave shfl (3 barriers)
    int hvd = (t < NB) ? hist_d[t] : 0;
    int hvs = (t < NB) ? hist_s[t] : 0;
    int vd = hvd, vs = hvs;
#pragma unroll
    for (int off = 1; off < 64; off <<= 1) {
        int ud = __shfl_up(vd, off, 64);
        int us = __shfl_up(vs, off, 64);
        if (lane >= off) { vd += ud; vs += us; }
    }
    if (lane == 63) { woffd[w] = vd; woffs[w] = vs; }
    __syncthreads();
    if (t < 64) {                   // wave 0 scans the 16 wave totals
        int sd = (t < 16) ? woffd[t] : 0;
        int ss = (t < 16) ? woffs[t] : 0;
        int od = sd, os = ss;
#pragma unroll
        for (int off = 1; off < 16; off <<= 1) {
            int ud = __shfl_up(sd, off, 64);
            int us = __shfl_up(ss, off, 64);
            if (lane >= off) { sd += ud; ss += us; }
        }
        if (t < 16) { woffd[t] = sd - od; woffs[t] = ss - os; }
    }
    __syncthreads();
    if (t < NB) {
        lbase_d[t] = vd + woffd[w] - hvd;
        lbase_s[t] = vs + woffs[w] - hvs;
    }
    // reserve global space per bucket
    for (int i = t; i < NB; i += 1024) {
        int c = hist_d[i];
        gbase_d[i] = i * CAPB + (c ? atomicAdd(&g_cur_d[i], c) : 0);
        c = hist_s[i];
        gbase_s[i] = i * CAPB + (c ? atomicAdd(&g_cur_s[i], c) : 0);
    }
    __syncthreads();
    // scatter into LDS stage, grouped by bucket (4-deep serial chain)
#pragma unroll
    for (int k = 0; k < 4; k++) {
        if (ed[k] >= 0) {
            int d = ed[k], s = es[k];
            int bd = d >> 8;
            int r = atomicAdd(&cur_d[bd], 1);
            int pos = lbase_d[bd] + r;
            stage[pos] = (long)(unsigned int)(s | ((d & 255) << 20)) |
                         ((long)__float_as_int(wv[k]) << 32);
            dbuck[pos] = (unsigned short)bd;
            int bs = s >> 8;
            int rs = atomicAdd(&cur_s[bs], 1);
            int ps = lbase_s[bs] + rs;
            sstage[ps] = (unsigned char)(s & 255);
            sbuck[ps] = (unsigned short)bs;
        }
    }
    __syncthreads();
    // stream out: consecutive slots in a bucket -> consecutive global addrs
    long* packl = (long*)pack_part;
    for (int i = t; i < total; i += 1024) {
        int b = dbuck[i];
        packl[(size_t)gbase_d[b] + (i - lbase_d[b])] = stage[i];
    }
    for (int i = t; i < total; i += 1024) {
        int b = sbuck[i];
        src_part[(size_t)gbase_s[b] + (i - lbase_s[b])] = sstage[i];
    }
}

// --- per bucket (1024 threads): dst CSR (hist + wave-0 scan + scatter in LDS)
//     + both norms + fused transform1 writing SPLIT h1a/h1b (16 dims each). ---
__global__ __launch_bounds__(1024) void csr_kernel(
                           const int2* __restrict__ pack_part,
                           const unsigned char* __restrict__ src_part,
                           const int* __restrict__ g_cur_d, const int* __restrict__ g_cur_s,
                           const float* __restrict__ feat, const float* __restrict__ W1,
                           int2* __restrict__ csr, int2* __restrict__ rs_cnt,
                           float* __restrict__ norm_src, float* __restrict__ norm_dst,
                           __half* __restrict__ h1a, __half* __restrict__ h1b, int n) {
    __shared__ int cnt[256];
    __shared__ int rowx[256];
    __shared__ int cur[256];
    __shared__ int cnt_s[256];
    __shared__ float nsrc[256];
    __shared__ float sW1[1024];
    extern __shared__ int2 stage[];  // CAPB entries (44 KB), reused as fp32 tile later
    int t = threadIdx.x, b = blockIdx.x;
    if (t < 256) { cnt[t] = 0; cur[t] = 0; cnt_s[t] = 0; }
    sW1[t] = W1[t];
    __syncthreads();
    int count = g_cur_d[b]; if (count > CAPB) count = CAPB;
    int count_s = g_cur_s[b]; if (count_s > CAPB) count_s = CAPB;
    const int2* p = pack_part + (size_t)b * CAPB;
    const unsigned char* sp = src_part + (size_t)b * CAPB;
    int2 pk[4];
#pragma unroll
    for (int u = 0; u < 4; u++) {
        int e = t + u * 1024;
        if (e < count) { pk[u] = p[e]; atomicAdd(&cnt[pk[u].x >> 20], 1); }
    }
    for (int e = t + 4096; e < count; e += 1024)    // rare tail past 4096
        atomicAdd(&cnt[p[e].x >> 20], 1);
    for (int e = t; e < count_s; e += 1024) atomicAdd(&cnt_s[sp[e]], 1);
    __syncthreads();
    if (t < 256) {
        int node = b * 256 + t;
        if (node < n) {
            int cs = cnt_s[t];
            float ns = rsqrtf((float)(cs > 1 ? cs : 1));
            nsrc[t] = ns;
            norm_src[node] = ns;
        } else nsrc[t] = 0.0f;
    }
    // wave 0: exclusive scan of cnt[256], 4 items/lane + shfl scan (1 barrier)
    if (t < 64) {
        int c0 = cnt[t * 4], c1 = cnt[t * 4 + 1], c2 = cnt[t * 4 + 2], c3 = cnt[t * 4 + 3];
        int tot = c0 + c1 + c2 + c3;
        int incl = tot;
#pragma unroll
        for (int off = 1; off < 64; off <<= 1) {
            int u = __shfl_up(incl, off, 64);
            if (t >= off) incl += u;
        }
        int excl = incl - tot;
        rowx[t * 4]     = excl;
        rowx[t * 4 + 1] = excl + c0;
        rowx[t * 4 + 2] = excl + c0 + c1;
        rowx[t * 4 + 3] = excl + c0 + c1 + c2;
    }
    __syncthreads();
    if (t < 256) {
        int node = b * 256 + t;
        if (node < n) {
            rs_cnt[node] = make_int2(b * CAPB + rowx[t], cnt[t]);
            norm_dst[node] = rsqrtf((float)(cnt[t] > 1 ? cnt[t] : 1));
        }
    }
    __syncthreads();
#pragma unroll
    for (int u = 0; u < 4; u++) {
        int e = t + u * 1024;
        if (e < count) {
            int2 v = pk[u];
            int dl = v.x >> 20;
            int r = atomicAdd(&cur[dl], 1);
            stage[rowx[dl] + r] = make_int2(v.x & 0x1FFFF, v.y);
        }
    }
    for (int e = t + 4096; e < count; e += 1024) {
        int2 v = p[e];
        int dl = v.x >> 20;
        int r = atomicAdd(&cur[dl], 1);
        stage[rowx[dl] + r] = make_int2(v.x & 0x1FFFF, v.y);
    }
    __syncthreads();
    int2* outp = csr + (size_t)b * CAPB;
    for (int e = t; e < count; e += 1024) outp[e] = stage[e];
    __syncthreads();
    // fused transform1: reuse stage as float tile sF[256][32] (32 KB)
    float* sF = (float*)stage;
    int node0 = b * 256;
    int lim = n - node0; if (lim > 256) lim = 256; if (lim < 0) lim = 0;
    for (int o = t; o < lim * 32; o += 1024) {
        int i = o >> 5, k = o & 31;
        sF[o] = feat[(size_t)(node0 + i) * 32 + k] * nsrc[i];
    }
    __syncthreads();
    for (int o = t; o < lim * 32; o += 1024) {
        int i = o >> 5, col = o & 31;
        float acc = 0.0f;
#pragma unroll
        for (int k = 0; k < 32; k++) acc += sF[i * 32 + k] * sW1[k * 32 + col];
        __half hv = __float2half(acc);
        if (col < 16) h1a[(size_t)(node0 + i) * 16 + col]        = hv;
        else          h1b[(size_t)(node0 + i) * 16 + (col - 16)] = hv;
    }
}

// --- gather1 pass A/B: 16 nodes/wave (4 lanes each, lane owns 4 dims via one
//     float2 = 4 halves). Each pass's gather table is 3.2MB -> L2-resident per
//     XCD (kernel boundary guarantees phase). A: partial o (fp32, nt-store).
//     B: + partial -> h2 fp16. ---
template<int PASS>
__global__ void gather1_pass(const __half* __restrict__ h1x, const int2* __restrict__ csr,
                             const int2* __restrict__ rs_cnt,
                             const float* __restrict__ norm_src, const float* __restrict__ norm_dst,
                             const float* __restrict__ W2, const float* __restrict__ b1,
                             float* __restrict__ part, __half* __restrict__ h2, int n) {
    __shared__ float sW2h[256];        // 16 rows x 16 cols of W2 (this pass's half)
    __shared__ float sB[16];
    __shared__ float sX[4][16][17];    // [wave][node][16 dims + pad]
    int t = threadIdx.x;
    if (t < 256) sW2h[t] = W2[PASS * 256 + t];
    if (t < 16)  sB[t] = b1[PASS * 16 + t];
    __syncthreads();
    int w = t >> 6, lane = t & 63;
    int q = lane >> 2;      // sub-node within wave (0..15)
    int dq = lane & 3;      // dim group: halves 4dq..4dq+3 of this 16-dim half
    int node = (blockIdx.x * 4 + w) * 16 + q;
    bool valid = node < n;
    int2 rc = valid ? rs_cnt[node] : make_int2(0, 0);
    long base = rc.x;
    int c = rc.y;
    const float2* tv = (const float2*)h1x;  // 4 float2 (16 halves) per row
    const long* csrl = (const long*)csr;
    float a00=0,a01=0,a02=0,a03=0, a10=0,a11=0,a12=0,a13=0;
    float a20=0,a21=0,a22=0,a23=0, a30=0,a31=0,a32=0,a33=0;
    int j = 0;
    for (; j + 3 < c; j += 4) {
        long q0 = nt_load_i64(csrl + base + j);
        long q1 = nt_load_i64(csrl + base + j + 1);
        long q2 = nt_load_i64(csrl + base + j + 2);
        long q3 = nt_load_i64(csrl + base + j + 3);
        float2 r0 = tv[(size_t)((int)q0 & 0xFFFFF) * 4 + dq];
        float2 r1 = tv[(size_t)((int)q1 & 0xFFFFF) * 4 + dq];
        float2 r2 = tv[(size_t)((int)q2 & 0xFFFFF) * 4 + dq];
        float2 r3 = tv[(size_t)((int)q3 & 0xFFFFF) * 4 + dq];
        float w0 = __int_as_float((int)(q0 >> 32)), w1 = __int_as_float((int)(q1 >> 32));
        float w2 = __int_as_float((int)(q2 >> 32)), w3 = __int_as_float((int)(q3 >> 32));
        float2 l0 = __half22float2(*(__half2*)&r0.x), h0 = __half22float2(*(__half2*)&r0.y);
        float2 l1 = __half22float2(*(__half2*)&r1.x), h1v = __half22float2(*(__half2*)&r1.y);
        float2 l2 = __half22float2(*(__half2*)&r2.x), h2v = __half22float2(*(__half2*)&r2.y);
        float2 l3 = __half22float2(*(__half2*)&r3.x), h3v = __half22float2(*(__half2*)&r3.y);
        a00 += l0.x * w0; a01 += l0.y * w0; a02 += h0.x * w0; a03 += h0.y * w0;
        a10 += l1.x * w1; a11 += l1.y * w1; a12 += h1v.x * w1; a13 += h1v.y * w1;
        a20 += l2.x * w2; a21 += l2.y * w2; a22 += h2v.x * w2; a23 += h2v.y * w2;
        a30 += l3.x * w3; a31 += l3.y * w3; a32 += h3v.x * w3; a33 += h3v.y * w3;
    }
    for (; j < c; j++) {
        long qq = nt_load_i64(csrl + base + j);
        float2 r = tv[(size_t)((int)qq & 0xFFFFF) * 4 + dq];
        float ww = __int_as_float((int)(qq >> 32));
        float2 l = __half22float2(*(__half2*)&r.x), h = __half22float2(*(__half2*)&r.y);
        a00 += l.x * ww; a01 += l.y * ww; a02 += h.x * ww; a03 += h.y * ww;
    }
    float s0 = (a00 + a10) + (a20 + a30);
    float s1 = (a01 + a11) + (a21 + a31);
    float s2 = (a02 + a12) + (a22 + a32);
    float s3 = (a03 + a13) + (a23 + a33);
    if (valid) {
        float nd = norm_dst[node], ns = norm_src[node];
        int d0 = 4 * dq;
        sX[w][q][d0]     = fmaxf(s0 * nd + sB[d0],     0.0f) * ns;
        sX[w][q][d0 + 1] = fmaxf(s1 * nd + sB[d0 + 1], 0.0f) * ns;
        sX[w][q][d0 + 2] = fmaxf(s2 * nd + sB[d0 + 2], 0.0f) * ns;
        sX[w][q][d0 + 3] = fmaxf(s3 * nd + sB[d0 + 3], 0.0f) * ns;
    }
    // wave-synchronous sX use (same wave wrote it); lane computes 4 output cols
    if (valid) {
        float o0 = 0.0f, o1 = 0.0f, o2 = 0.0f, o3 = 0.0f;
        int c0 = 4 * dq;
#pragma unroll
        for (int k = 0; k < 16; k++) {
            float x = sX[w][q][k];
            o0 += x * sW2h[k * 16 + c0];
            o1 += x * sW2h[k * 16 + c0 + 1];
            o2 += x * sW2h[k * 16 + c0 + 2];
            o3 += x * sW2h[k * 16 + c0 + 3];
        }
        if (PASS == 0) {
            f32x4 pv = { o0, o1, o2, o3 };
            __builtin_nontemporal_store(pv, (f32x4*)part + (size_t)node * 4 + dq);
        } else {
            f32x4 pv = __builtin_nontemporal_load((const f32x4*)part + (size_t)node * 4 + dq);
            o0 += pv.x; o1 += pv.y; o2 += pv.z; o3 += pv.w;
            __half2 lo = __floats2half2_rn(o0, o1);
            __half2 hi = __floats2half2_rn(o2, o3);
            float2 st;
            st.x = __uint_as_float(*(unsigned int*)&lo);
            st.y = __uint_as_float(*(unsigned int*)&hi);
            ((float2*)h2)[(size_t)node * 4 + dq] = st;
        }
    }
}

// --- gather2 + fused epilogue: 16 nodes per wave (4 lanes each, lane owns
//     4 dims via one float2 load) -> float4 store, no LDS. h2 = 3.2MB L2-fits. ---
__global__ void gather2_kernel(const __half* __restrict__ h2, const int2* __restrict__ csr,
                               const int2* __restrict__ rs_cnt,
                               const float* __restrict__ norm_dst, const float* __restrict__ b2,
                               float* __restrict__ out, int n) {
    int t = threadIdx.x;
    int w = t >> 6, lane = t & 63;
    int q = lane >> 2;     // sub-node within wave (0..15)
    int dq = lane & 3;     // float2 index (dims 4dq..4dq+3)
    int node = (blockIdx.x * 4 + w) * 16 + q;
    bool valid = node < n;
    int2 rc = valid ? rs_cnt[node] : make_int2(0, 0);
    long base = rc.x;
    int c = rc.y;
    const float2* tv = (const float2*)h2;   // 4 float2 (16 halves) per row
    const long* csrl = (const long*)csr;
    float a00=0,a01=0,a02=0,a03=0, a10=0,a11=0,a12=0,a13=0;
    float a20=0,a21=0,a22=0,a23=0, a30=0,a31=0,a32=0,a33=0;
    int j = 0;
    for (; j + 3 < c; j += 4) {
        long q0 = nt_load_i64(csrl + base + j);
        long q1 = nt_load_i64(csrl + base + j + 1);
        long q2 = nt_load_i64(csrl + base + j + 2);
        long q3 = nt_load_i64(csrl + base + j + 3);
        float2 r0 = tv[(size_t)((int)q0 & 0xFFFFF) * 4 + dq];
        float2 r1 = tv[(size_t)((int)q1 & 0xFFFFF) * 4 + dq];
        float2 r2 = tv[(size_t)((int)q2 & 0xFFFFF) * 4 + dq];
        float2 r3 = tv[(size_t)((int)q3 & 0xFFFFF) * 4 + dq];
        float w0 = __int_as_float((int)(q0 >> 32)), w1 = __int_as_float((int)(q1 >> 32));
        float w2 = __int_as_float((int)(q2 >> 32)), w3 = __int_as_float((int)(q3 >> 32));
        float2 l0 = __half22float2(*(__half2*)&r0.x), h0 = __half22float2(*(__half2*)&r0.y);
        float2 l1 = __half22float2(*(__half2*)&r1.x), h1v = __half22float2(*(__half2*)&r1.y);
        float2 l2 = __half22float2(*(__half2*)&r2.x), h2v = __half22float2(*(__half2*)&r2.y);
        float2 l3 = __half22float2(*(__half2*)&r3.x), h3v = __half22float2(*(__half2*)&r3.y);
        a00 += l0.x * w0; a01 += l0.y * w0; a02 += h0.x * w0; a03 += h0.y * w0;
        a10 += l1.x * w1; a11 += l1.y * w1; a12 += h1v.x * w1; a13 += h1v.y * w1;
        a20 += l2.x * w2; a21 += l2.y * w2; a22 += h2v.x * w2; a23 += h2v.y * w2;
        a30 += l3.x * w3; a31 += l3.y * w3; a32 += h3v.x * w3; a33 += h3v.y * w3;
    }
    for (; j < c; j++) {
        long qq = nt_load_i64(csrl + base + j);
        float2 r = tv[(size_t)((int)qq & 0xFFFFF) * 4 + dq];
        float ww = __int_as_float((int)(qq >> 32));
        float2 l = __half22float2(*(__half2*)&r.x), h = __half22float2(*(__half2*)&r.y);
        a00 += l.x * ww; a01 += l.y * ww; a02 += h.x * ww; a03 += h.y * ww;
    }
    if (valid) {
        float nd = norm_dst[node];
        int d0 = 4 * dq;
        float4 o;
        o.x = ((a00 + a10) + (a20 + a30)) * nd + b2[d0];
        o.y = ((a01 + a11) + (a21 + a31)) * nd + b2[d0 + 1];
        o.z = ((a02 + a12) + (a22 + a32)) * nd + b2[d0 + 2];
        o.w = ((a03 + a13) + (a23 + a33)) * nd + b2[d0 + 3];
        ((float4*)out)[(size_t)node * 4 + dq] = o;
    }
}

extern "C" void kernel_launch(void* const* d_in, const int* in_sizes, int n_in,
                              void* d_out, int out_size, void* d_ws, size_t ws_size,
                              hipStream_t stream) {
    const float* feat = (const float*)d_in[0];
    const int*   src  = (const int*)d_in[1];
    const int*   dst  = (const int*)d_in[2];
    const float* ew   = (const float*)d_in[3];
    const float* W1   = (const float*)d_in[4];
    const float* b1   = (const float*)d_in[5];
    const float* W2   = (const float*)d_in[6];
    const float* b2   = (const float*)d_in[7];
    float* out = (float*)d_out;

    const int n = in_sizes[0] / 32;  // 100000
    const int m = in_sizes[1];       // 1600000

    // ws: pack_part[NB*CAPB int2] | csr[NB*CAPB int2] | h1a half[16n] |
    //     h1b half[16n] | h2 half[16n] | part float[16n] | norm_src[n] |
    //     norm_dst[n] | rs_cnt int2[n] | g_cur_d[NB] | g_cur_s[NB] |
    //     src_part uchar[NB*CAPB]
    char* wsb = (char*)d_ws;
    int2*   pack_part = (int2*)wsb;
    int2*   csr       = pack_part + (size_t)NB * CAPB;
    __half* h1a       = (__half*)(csr + (size_t)NB * CAPB);
    __half* h1b       = h1a + 16 * (size_t)n;
    __half* h2        = h1b + 16 * (size_t)n;
    float*  part      = (float*)(h2 + 16 * (size_t)n);
    float*  norm_src  = part + 16 * (size_t)n;
    float*  norm_dst  = norm_src + n;
    int2*   rs_cnt    = (int2*)(norm_dst + n);
    int*    g_cur_d   = (int*)(rs_cnt + n);
    int*    g_cur_s   = g_cur_d + NB;
    unsigned char* src_part = (unsigned char*)(g_cur_s + NB);

    hipMemsetAsync(g_cur_d, 0, 2 * NB * sizeof(int), stream);

    partition_kernel<<<(m + EPB - 1) / EPB, 1024, 0, stream>>>(src, dst, ew, g_cur_d, g_cur_s,
                                                               pack_part, src_part, m);
    csr_kernel<<<NB, 1024, CAPB * sizeof(int2), stream>>>(pack_part, src_part, g_cur_d, g_cur_s,
                                                          feat, W1, csr, rs_cnt,
                                                          norm_src, norm_dst, h1a, h1b, n);
    int g1grid = (n + 63) / 64;
    gather1_pass<0><<<g1grid, 256, 0, stream>>>(h1a, csr, rs_cnt, norm_src, norm_dst,
                                                W2, b1, part, h2, n);
    gather1_pass<1><<<g1grid, 256, 0, stream>>>(h1b, csr, rs_cnt, norm_src, norm_dst,
                                                W2, b1, part, h2, n);
    gather2_kernel<<<(n + 63) / 64, 256, 0, stream>>>(h2, csr, rs_cnt, norm_dst, b2, out, n);
}

// Round 11
// 183.302 us; speedup vs baseline: 1.1431x; 1.1431x over previous
//
#include <hip/hip_runtime.h>
#include <hip/hip_fp16.h>

// GCN 2-layer, r5 baseline (186.8us) with ONE lever: gather1 restructured for
// 2x memory-level parallelism. r7-r10 established: g1 = 41us, latency-bound
// (VALU 23%, HBM 32%, occ 66%), fetch mostly compulsory per-XCD -> L2 tiling
// dead end (r8 +5us, r10 +23us). New g1: 16 nodes/wave (4 lanes/node),
// float4 row loads -> 64 edge-rows in flight/wave (was 32), half the request
// slots per row. partition/csr/gather2 byte-identical to r5.

#define NB   391      // buckets = ceil(100000/256); bucket = id >> 8
#define CAPB 5504     // padded per-bucket edge capacity (avg 4092, +22 sigma)
#define EPB  4096     // edges per partition block (4/thread at 1024 threads)

typedef float f32x4 __attribute__((ext_vector_type(4)));

__device__ __forceinline__ long nt_load_i64(const long* p) {
    return __builtin_nontemporal_load(p);
}

// --- pass 1: partition edges by dst-bucket; LDS-staged, coalesced run writes ---
__global__ __launch_bounds__(1024) void partition_kernel(
        const int* __restrict__ src, const int* __restrict__ dst,
        const float* __restrict__ ew,
        int* __restrict__ g_cur_d, int* __restrict__ g_cur_s,
        int2* __restrict__ pack_part, unsigned char* __restrict__ src_part, int m) {
    __shared__ int hist_d[NB], hist_s[NB];
    __shared__ int lbase_d[NB], lbase_s[NB];
    __shared__ int gbase_d[NB], gbase_s[NB];
    __shared__ int cur_d[NB], cur_s[NB];
    __shared__ int woffd[16], woffs[16];
    __shared__ long stage[EPB];            // 32 KB
    __shared__ unsigned short dbuck[EPB];  // 8 KB
    __shared__ unsigned char  sstage[EPB]; // 4 KB
    __shared__ unsigned short sbuck[EPB];  // 8 KB
    int t = threadIdx.x, lane = t & 63, w = t >> 6;
    for (int i = t; i < NB; i += 1024) {
        hist_d[i] = 0; hist_s[i] = 0; cur_d[i] = 0; cur_s[i] = 0;
    }
    __syncthreads();
    int base_e = blockIdx.x * EPB;
    int total = m - base_e; if (total > EPB) total = EPB;
    int es[4], ed[4]; float wv[4];
#pragma unroll
    for (int k = 0; k < 4; k++) {
        int e = base_e + k * 1024 + t;
        if (e < m) { es[k] = src[e]; ed[k] = dst[e]; wv[k] = ew[e]; }
        else ed[k] = -1;
    }
#pragma unroll
    for (int k = 0; k < 4; k++) {
        if (ed[k] >= 0) {
            atomicAdd(&hist_d[ed[k] >> 8], 1);
            atomicAdd(&hist_s[es[k] >> 8], 1);
        }
    }
    __syncthreads();
    // fused exclusive scans of hist_d/hist_s (NB=391) via wave shfl (3 barriers)
    int hvd = (t < NB) ? hist_d[t] : 0;
    int hvs = (t < NB) ? hist_s[t] : 0;
    int vd = hvd, vs = hvs;
#pragma unroll
    for (int off = 1; off < 64; off <<= 1) {
        int ud = __shfl_up(vd, off, 64);
        int us = __shfl_up(vs, off, 64);
        if (lane >= off) { vd += ud; vs += us; }
    }
    if (lane == 63) { woffd[w] = vd; woffs[w] = vs; }
    __syncthreads();
    if (t < 64) {                   // wave 0 scans the 16 wave totals
        int sd = (t < 16) ? woffd[t] : 0;
        int ss = (t < 16) ? woffs[t] : 0;
        int od = sd, os = ss;
#pragma unroll
        for (int off = 1; off < 16; off <<= 1) {
            int ud = __shfl_up(sd, off, 64);
            int us = __shfl_up(ss, off, 64);
            if (lane >= off) { sd += ud; ss += us; }
        }
        if (t < 16) { woffd[t] = sd - od; woffs[t] = ss - os; }
    }
    __syncthreads();
    if (t < NB) {
        lbase_d[t] = vd + woffd[w] - hvd;
        lbase_s[t] = vs + woffs[w] - hvs;
    }
    // reserve global space per bucket
    for (int i = t; i < NB; i += 1024) {
        int c = hist_d[i];
        gbase_d[i] = i * CAPB + (c ? atomicAdd(&g_cur_d[i], c) : 0);
        c = hist_s[i];
        gbase_s[i] = i * CAPB + (c ? atomicAdd(&g_cur_s[i], c) : 0);
    }
    __syncthreads();
    // scatter into LDS stage, grouped by bucket (4-deep serial chain)
#pragma unroll
    for (int k = 0; k < 4; k++) {
        if (ed[k] >= 0) {
            int d = ed[k], s = es[k];
            int bd = d >> 8;
            int r = atomicAdd(&cur_d[bd], 1);
            int pos = lbase_d[bd] + r;
            stage[pos] = (long)(unsigned int)(s | ((d & 255) << 20)) |
                         ((long)__float_as_int(wv[k]) << 32);
            dbuck[pos] = (unsigned short)bd;
            int bs = s >> 8;
            int rs = atomicAdd(&cur_s[bs], 1);
            int ps = lbase_s[bs] + rs;
            sstage[ps] = (unsigned char)(s & 255);
            sbuck[ps] = (unsigned short)bs;
        }
    }
    __syncthreads();
    // stream out: consecutive slots in a bucket -> consecutive global addrs
    long* packl = (long*)pack_part;
    for (int i = t; i < total; i += 1024) {
        int b = dbuck[i];
        packl[(size_t)gbase_d[b] + (i - lbase_d[b])] = stage[i];
    }
    for (int i = t; i < total; i += 1024) {
        int b = sbuck[i];
        src_part[(size_t)gbase_s[b] + (i - lbase_s[b])] = sstage[i];
    }
}

// --- per bucket (1024 threads): dst CSR (hist + wave-0 scan + scatter in LDS)
//     + both norms + fused transform1. pack entries register-cached (pk[4]). ---
__global__ __launch_bounds__(1024) void csr_kernel(
                           const int2* __restrict__ pack_part,
                           const unsigned char* __restrict__ src_part,
                           const int* __restrict__ g_cur_d, const int* __restrict__ g_cur_s,
                           const float* __restrict__ feat, const float* __restrict__ W1,
                           int2* __restrict__ csr, int2* __restrict__ rs_cnt,
                           float* __restrict__ norm_src, float* __restrict__ norm_dst,
                           __half* __restrict__ h1, int n) {
    __shared__ int cnt[256];
    __shared__ int rowx[256];
    __shared__ int cur[256];
    __shared__ int cnt_s[256];
    __shared__ float nsrc[256];
    __shared__ float sW1[1024];
    extern __shared__ int2 stage[];  // CAPB entries (44 KB), reused as fp32 tile later
    int t = threadIdx.x, b = blockIdx.x;
    if (t < 256) { cnt[t] = 0; cur[t] = 0; cnt_s[t] = 0; }
    sW1[t] = W1[t];
    __syncthreads();
    int count = g_cur_d[b]; if (count > CAPB) count = CAPB;
    int count_s = g_cur_s[b]; if (count_s > CAPB) count_s = CAPB;
    const int2* p = pack_part + (size_t)b * CAPB;
    const unsigned char* sp = src_part + (size_t)b * CAPB;
    int2 pk[4];
#pragma unroll
    for (int u = 0; u < 4; u++) {
        int e = t + u * 1024;
        if (e < count) { pk[u] = p[e]; atomicAdd(&cnt[pk[u].x >> 20], 1); }
    }
    for (int e = t + 4096; e < count; e += 1024)    // rare tail past 4096
        atomicAdd(&cnt[p[e].x >> 20], 1);
    for (int e = t; e < count_s; e += 1024) atomicAdd(&cnt_s[sp[e]], 1);
    __syncthreads();
    if (t < 256) {
        int node = b * 256 + t;
        if (node < n) {
            int cs = cnt_s[t];
            float ns = rsqrtf((float)(cs > 1 ? cs : 1));
            nsrc[t] = ns;
            norm_src[node] = ns;
        } else nsrc[t] = 0.0f;
    }
    // wave 0: exclusive scan of cnt[256], 4 items/lane + shfl scan (1 barrier)
    if (t < 64) {
        int c0 = cnt[t * 4], c1 = cnt[t * 4 + 1], c2 = cnt[t * 4 + 2], c3 = cnt[t * 4 + 3];
        int tot = c0 + c1 + c2 + c3;
        int incl = tot;
#pragma unroll
        for (int off = 1; off < 64; off <<= 1) {
            int u = __shfl_up(incl, off, 64);
            if (t >= off) incl += u;
        }
        int excl = incl - tot;
        rowx[t * 4]     = excl;
        rowx[t * 4 + 1] = excl + c0;
        rowx[t * 4 + 2] = excl + c0 + c1;
        rowx[t * 4 + 3] = excl + c0 + c1 + c2;
    }
    __syncthreads();
    if (t < 256) {
        int node = b * 256 + t;
        if (node < n) {
            rs_cnt[node] = make_int2(b * CAPB + rowx[t], cnt[t]);
            norm_dst[node] = rsqrtf((float)(cnt[t] > 1 ? cnt[t] : 1));
        }
    }
    __syncthreads();
#pragma unroll
    for (int u = 0; u < 4; u++) {
        int e = t + u * 1024;
        if (e < count) {
            int2 v = pk[u];
            int dl = v.x >> 20;
            int r = atomicAdd(&cur[dl], 1);
            stage[rowx[dl] + r] = make_int2(v.x & 0x1FFFF, v.y);
        }
    }
    for (int e = t + 4096; e < count; e += 1024) {
        int2 v = p[e];
        int dl = v.x >> 20;
        int r = atomicAdd(&cur[dl], 1);
        stage[rowx[dl] + r] = make_int2(v.x & 0x1FFFF, v.y);
    }
    __syncthreads();
    int2* outp = csr + (size_t)b * CAPB;
    for (int e = t; e < count; e += 1024) outp[e] = stage[e];
    __syncthreads();
    // fused transform1: reuse stage as float tile sF[256][32] (32 KB)
    float* sF = (float*)stage;
    int node0 = b * 256;
    int lim = n - node0; if (lim > 256) lim = 256; if (lim < 0) lim = 0;
    for (int o = t; o < lim * 32; o += 1024) {
        int i = o >> 5, k = o & 31;
        sF[o] = feat[(size_t)(node0 + i) * 32 + k] * nsrc[i];
    }
    __syncthreads();
    for (int o = t; o < lim * 32; o += 1024) {
        int i = o >> 5, col = o & 31;
        float acc = 0.0f;
#pragma unroll
        for (int k = 0; k < 32; k++) acc += sF[i * 32 + k] * sW1[k * 32 + col];
        h1[(size_t)(node0 + i) * 32 + col] = __float2half(acc);
    }
}

// --- gather1 + fused transform2: 16 nodes per wave (4 lanes each, lane owns
//     8 dims via one float4 = 4xhalf2 load) -> 64 edge-rows in flight/wave
//     (2x r5) with half the request slots per row. ---
__global__ void gather1_fused_kernel(const __half* __restrict__ h1, const int2* __restrict__ csr,
                                     const int2* __restrict__ rs_cnt,
                                     const float* __restrict__ norm_src, const float* __restrict__ norm_dst,
                                     const float* __restrict__ W2, const float* __restrict__ b1,
                                     __half* __restrict__ h2, int n) {
    __shared__ float sW2[32 * 16];
    __shared__ float sB1[32];
    __shared__ float sX[4][16][33];
    int t = threadIdx.x;
    for (int i = t; i < 512; i += 256) sW2[i] = W2[i];
    if (t < 32) sB1[t] = b1[t];
    __syncthreads();
    int w = t >> 6, lane = t & 63;
    int q = lane >> 2;      // sub-node within wave (0..15)
    int dq = lane & 3;      // float4 index (halves 8dq..8dq+7)
    int node = (blockIdx.x * 4 + w) * 16 + q;
    bool valid = node < n;
    int2 rc = valid ? rs_cnt[node] : make_int2(0, 0);
    long base = rc.x;
    int c = rc.y;
    const f32x4* tv = (const f32x4*)h1;     // 4 float4 (32 halves) per row
    const long* csrl = (const long*)csr;
    float a00=0,a01=0,a02=0,a03=0,a04=0,a05=0,a06=0,a07=0;
    float a10=0,a11=0,a12=0,a13=0,a14=0,a15=0,a16=0,a17=0;
    float a20=0,a21=0,a22=0,a23=0,a24=0,a25=0,a26=0,a27=0;
    float a30=0,a31=0,a32=0,a33=0,a34=0,a35=0,a36=0,a37=0;
    int j = 0;
    for (; j + 3 < c; j += 4) {
        long q0 = nt_load_i64(csrl + base + j);
        long q1 = nt_load_i64(csrl + base + j + 1);
        long q2 = nt_load_i64(csrl + base + j + 2);
        long q3 = nt_load_i64(csrl + base + j + 3);
        f32x4 r0 = tv[(size_t)((int)q0 & 0xFFFFF) * 4 + dq];
        f32x4 r1 = tv[(size_t)((int)q1 & 0xFFFFF) * 4 + dq];
        f32x4 r2 = tv[(size_t)((int)q2 & 0xFFFFF) * 4 + dq];
        f32x4 r3 = tv[(size_t)((int)q3 & 0xFFFFF) * 4 + dq];
        float w0 = __int_as_float((int)(q0 >> 32)), w1 = __int_as_float((int)(q1 >> 32));
        float w2 = __int_as_float((int)(q2 >> 32)), w3 = __int_as_float((int)(q3 >> 32));
        const __half2* p0 = (const __half2*)&r0;
        const __half2* p1 = (const __half2*)&r1;
        const __half2* p2 = (const __half2*)&r2;
        const __half2* p3 = (const __half2*)&r3;
        float2 f;
        f = __half22float2(p0[0]); a00 += f.x * w0; a01 += f.y * w0;
        f = __half22float2(p0[1]); a02 += f.x * w0; a03 += f.y * w0;
        f = __half22float2(p0[2]); a04 += f.x * w0; a05 += f.y * w0;
        f = __half22float2(p0[3]); a06 += f.x * w0; a07 += f.y * w0;
        f = __half22float2(p1[0]); a10 += f.x * w1; a11 += f.y * w1;
        f = __half22float2(p1[1]); a12 += f.x * w1; a13 += f.y * w1;
        f = __half22float2(p1[2]); a14 += f.x * w1; a15 += f.y * w1;
        f = __half22float2(p1[3]); a16 += f.x * w1; a17 += f.y * w1;
        f = __half22float2(p2[0]); a20 += f.x * w2; a21 += f.y * w2;
        f = __half22float2(p2[1]); a22 += f.x * w2; a23 += f.y * w2;
        f = __half22float2(p2[2]); a24 += f.x * w2; a25 += f.y * w2;
        f = __half22float2(p2[3]); a26 += f.x * w2; a27 += f.y * w2;
        f = __half22float2(p3[0]); a30 += f.x * w3; a31 += f.y * w3;
        f = __half22float2(p3[1]); a32 += f.x * w3; a33 += f.y * w3;
        f = __half22float2(p3[2]); a34 += f.x * w3; a35 += f.y * w3;
        f = __half22float2(p3[3]); a36 += f.x * w3; a37 += f.y * w3;
    }
    for (; j < c; j++) {
        long qq = nt_load_i64(csrl + base + j);
        f32x4 r = tv[(size_t)((int)qq & 0xFFFFF) * 4 + dq];
        float ww = __int_as_float((int)(qq >> 32));
        const __half2* pp = (const __half2*)&r;
        float2 f;
        f = __half22float2(pp[0]); a00 += f.x * ww; a01 += f.y * ww;
        f = __half22float2(pp[1]); a02 += f.x * ww; a03 += f.y * ww;
        f = __half22float2(pp[2]); a04 += f.x * ww; a05 += f.y * ww;
        f = __half22float2(pp[3]); a06 += f.x * ww; a07 += f.y * ww;
    }
    float s0 = (a00 + a10) + (a20 + a30);
    float s1 = (a01 + a11) + (a21 + a31);
    float s2 = (a02 + a12) + (a22 + a32);
    float s3 = (a03 + a13) + (a23 + a33);
    float s4 = (a04 + a14) + (a24 + a34);
    float s5 = (a05 + a15) + (a25 + a35);
    float s6 = (a06 + a16) + (a26 + a36);
    float s7 = (a07 + a17) + (a27 + a37);
    if (valid) {
        float nd = norm_dst[node], ns = norm_src[node];
        int d0 = 8 * dq;
        sX[w][q][d0]     = fmaxf(s0 * nd + sB1[d0],     0.0f) * ns;
        sX[w][q][d0 + 1] = fmaxf(s1 * nd + sB1[d0 + 1], 0.0f) * ns;
        sX[w][q][d0 + 2] = fmaxf(s2 * nd + sB1[d0 + 2], 0.0f) * ns;
        sX[w][q][d0 + 3] = fmaxf(s3 * nd + sB1[d0 + 3], 0.0f) * ns;
        sX[w][q][d0 + 4] = fmaxf(s4 * nd + sB1[d0 + 4], 0.0f) * ns;
        sX[w][q][d0 + 5] = fmaxf(s5 * nd + sB1[d0 + 5], 0.0f) * ns;
        sX[w][q][d0 + 6] = fmaxf(s6 * nd + sB1[d0 + 6], 0.0f) * ns;
        sX[w][q][d0 + 7] = fmaxf(s7 * nd + sB1[d0 + 7], 0.0f) * ns;
    }
    // wave-synchronous LDS use (same wave wrote sX[w][q]); lane computes 4 cols
    if (valid) {
        float o0 = 0.0f, o1 = 0.0f, o2 = 0.0f, o3 = 0.0f;
        int c0 = 4 * dq;
#pragma unroll
        for (int k = 0; k < 32; k++) {
            float x = sX[w][q][k];
            o0 += x * sW2[k * 16 + c0];
            o1 += x * sW2[k * 16 + c0 + 1];
            o2 += x * sW2[k * 16 + c0 + 2];
            o3 += x * sW2[k * 16 + c0 + 3];
        }
        __half2 lo = __floats2half2_rn(o0, o1);
        __half2 hi = __floats2half2_rn(o2, o3);
        float2 st;
        st.x = __uint_as_float(*(unsigned int*)&lo);
        st.y = __uint_as_float(*(unsigned int*)&hi);
        ((float2*)h2)[(size_t)node * 4 + dq] = st;
    }
}

// --- gather2 + fused epilogue: 16 nodes per wave (4 lanes each, lane owns
//     4 dims via one float2 load) -> float4 store, no LDS. (r5 body) ---
__global__ void gather2_kernel(const __half* __restrict__ h2, const int2* __restrict__ csr,
                               const int2* __restrict__ rs_cnt,
                               const float* __restrict__ norm_dst, const float* __restrict__ b2,
                               float* __restrict__ out, int n) {
    int t = threadIdx.x;
    int w = t >> 6, lane = t & 63;
    int q = lane >> 2;     // sub-node within wave (0..15)
    int dq = lane & 3;     // float2 index (dims 4dq..4dq+3)
    int node = (blockIdx.x * 4 + w) * 16 + q;
    bool valid = node < n;
    int2 rc = valid ? rs_cnt[node] : make_int2(0, 0);
    long base = rc.x;
    int c = rc.y;
    const float2* tv = (const float2*)h2;   // 4 float2 (16 halves) per row
    const long* csrl = (const long*)csr;
    float a00=0,a01=0,a02=0,a03=0, a10=0,a11=0,a12=0,a13=0;
    float a20=0,a21=0,a22=0,a23=0, a30=0,a31=0,a32=0,a33=0;
    int j = 0;
    for (; j + 3 < c; j += 4) {
        long q0 = nt_load_i64(csrl + base + j);
        long q1 = nt_load_i64(csrl + base + j + 1);
        long q2 = nt_load_i64(csrl + base + j + 2);
        long q3 = nt_load_i64(csrl + base + j + 3);
        float2 r0 = tv[(size_t)((int)q0 & 0xFFFFF) * 4 + dq];
        float2 r1 = tv[(size_t)((int)q1 & 0xFFFFF) * 4 + dq];
        float2 r2 = tv[(size_t)((int)q2 & 0xFFFFF) * 4 + dq];
        float2 r3 = tv[(size_t)((int)q3 & 0xFFFFF) * 4 + dq];
        float w0 = __int_as_float((int)(q0 >> 32)), w1 = __int_as_float((int)(q1 >> 32));
        float w2 = __int_as_float((int)(q2 >> 32)), w3 = __int_as_float((int)(q3 >> 32));
        float2 l0 = __half22float2(*(__half2*)&r0.x), h0 = __half22float2(*(__half2*)&r0.y);
        float2 l1 = __half22float2(*(__half2*)&r1.x), h1v = __half22float2(*(__half2*)&r1.y);
        float2 l2 = __half22float2(*(__half2*)&r2.x), h2v = __half22float2(*(__half2*)&r2.y);
        float2 l3 = __half22float2(*(__half2*)&r3.x), h3v = __half22float2(*(__half2*)&r3.y);
        a00 += l0.x * w0; a01 += l0.y * w0; a02 += h0.x * w0; a03 += h0.y * w0;
        a10 += l1.x * w1; a11 += l1.y * w1; a12 += h1v.x * w1; a13 += h1v.y * w1;
        a20 += l2.x * w2; a21 += l2.y * w2; a22 += h2v.x * w2; a23 += h2v.y * w2;
        a30 += l3.x * w3; a31 += l3.y * w3; a32 += h3v.x * w3; a33 += h3v.y * w3;
    }
    for (; j < c; j++) {
        long qq = nt_load_i64(csrl + base + j);
        float2 r = tv[(size_t)((int)qq & 0xFFFFF) * 4 + dq];
        float ww = __int_as_float((int)(qq >> 32));
        float2 l = __half22float2(*(__half2*)&r.x), h = __half22float2(*(__half2*)&r.y);
        a00 += l.x * ww; a01 += l.y * ww; a02 += h.x * ww; a03 += h.y * ww;
    }
    if (valid) {
        float nd = norm_dst[node];
        int d0 = 4 * dq;
        float4 o;
        o.x = ((a00 + a10) + (a20 + a30)) * nd + b2[d0];
        o.y = ((a01 + a11) + (a21 + a31)) * nd + b2[d0 + 1];
        o.z = ((a02 + a12) + (a22 + a32)) * nd + b2[d0 + 2];
        o.w = ((a03 + a13) + (a23 + a33)) * nd + b2[d0 + 3];
        ((float4*)out)[(size_t)node * 4 + dq] = o;
    }
}

extern "C" void kernel_launch(void* const* d_in, const int* in_sizes, int n_in,
                              void* d_out, int out_size, void* d_ws, size_t ws_size,
                              hipStream_t stream) {
    const float* feat = (const float*)d_in[0];
    const int*   src  = (const int*)d_in[1];
    const int*   dst  = (const int*)d_in[2];
    const float* ew   = (const float*)d_in[3];
    const float* W1   = (const float*)d_in[4];
    const float* b1   = (const float*)d_in[5];
    const float* W2   = (const float*)d_in[6];
    const float* b2   = (const float*)d_in[7];
    float* out = (float*)d_out;

    const int n = in_sizes[0] / 32;  // 100000
    const int m = in_sizes[1];       // 1600000

    // ws: pack_part[NB*CAPB int2] | csr[NB*CAPB int2] | h1 half[32n] | h2 half[16n] |
    //     norm_src[n] | norm_dst[n] | rs_cnt int2[n] | g_cur_d[NB] | g_cur_s[NB] |
    //     src_part uchar[NB*CAPB]
    char* wsb = (char*)d_ws;
    int2*   pack_part = (int2*)wsb;
    int2*   csr       = pack_part + (size_t)NB * CAPB;
    __half* h1        = (__half*)(csr + (size_t)NB * CAPB);
    __half* h2        = h1 + 32 * (size_t)n;
    float*  norm_src  = (float*)(h2 + 16 * (size_t)n);
    float*  norm_dst  = norm_src + n;
    int2*   rs_cnt    = (int2*)(norm_dst + n);
    int*    g_cur_d   = (int*)(rs_cnt + n);
    int*    g_cur_s   = g_cur_d + NB;
    unsigned char* src_part = (unsigned char*)(g_cur_s + NB);

    hipMemsetAsync(g_cur_d, 0, 2 * NB * sizeof(int), stream);

    partition_kernel<<<(m + EPB - 1) / EPB, 1024, 0, stream>>>(src, dst, ew, g_cur_d, g_cur_s,
                                                               pack_part, src_part, m);
    csr_kernel<<<NB, 1024, CAPB * sizeof(int2), stream>>>(pack_part, src_part, g_cur_d, g_cur_s,
                                                          feat, W1, csr, rs_cnt,
                                                          norm_src, norm_dst, h1, n);
    gather1_fused_kernel<<<(n + 63) / 64, 256, 0, stream>>>(h1, csr, rs_cnt,
                                                            norm_src, norm_dst, W2, b1, h2, n);
    gather2_kernel<<<(n + 63) / 64, 256, 0, stream>>>(h2, csr, rs_cnt, norm_dst, b2, out, n);
}

// Round 12
// 182.767 us; speedup vs baseline: 1.1464x; 1.0029x over previous
//
#include <hip/hip_runtime.h>
#include <hip/hip_fp16.h>

// GCN 2-layer. r11 (183.3us) with ONE lever: gather2 restructured for 2x MLP,
// same mechanism as r11's validated g1 win (more rows in flight, fewer
// requests/row). g2: 32 nodes/wave (2 lanes/node), float4 row loads -> 128
// edge-rows in flight/wave (was 64), 2 requests/row (was 4). Epilogue: lane
// owns 8 output dims, two float4 stores. partition/csr/gather1 identical r11.

#define NB   391      // buckets = ceil(100000/256); bucket = id >> 8
#define CAPB 5504     // padded per-bucket edge capacity (avg 4092, +22 sigma)
#define EPB  4096     // edges per partition block (4/thread at 1024 threads)

typedef float f32x4 __attribute__((ext_vector_type(4)));

__device__ __forceinline__ long nt_load_i64(const long* p) {
    return __builtin_nontemporal_load(p);
}

// --- pass 1: partition edges by dst-bucket; LDS-staged, coalesced run writes ---
__global__ __launch_bounds__(1024) void partition_kernel(
        const int* __restrict__ src, const int* __restrict__ dst,
        const float* __restrict__ ew,
        int* __restrict__ g_cur_d, int* __restrict__ g_cur_s,
        int2* __restrict__ pack_part, unsigned char* __restrict__ src_part, int m) {
    __shared__ int hist_d[NB], hist_s[NB];
    __shared__ int lbase_d[NB], lbase_s[NB];
    __shared__ int gbase_d[NB], gbase_s[NB];
    __shared__ int cur_d[NB], cur_s[NB];
    __shared__ int woffd[16], woffs[16];
    __shared__ long stage[EPB];            // 32 KB
    __shared__ unsigned short dbuck[EPB];  // 8 KB
    __shared__ unsigned char  sstage[EPB]; // 4 KB
    __shared__ unsigned short sbuck[EPB];  // 8 KB
    int t = threadIdx.x, lane = t & 63, w = t >> 6;
    for (int i = t; i < NB; i += 1024) {
        hist_d[i] = 0; hist_s[i] = 0; cur_d[i] = 0; cur_s[i] = 0;
    }
    __syncthreads();
    int base_e = blockIdx.x * EPB;
    int total = m - base_e; if (total > EPB) total = EPB;
    int es[4], ed[4]; float wv[4];
#pragma unroll
    for (int k = 0; k < 4; k++) {
        int e = base_e + k * 1024 + t;
        if (e < m) { es[k] = src[e]; ed[k] = dst[e]; wv[k] = ew[e]; }
        else ed[k] = -1;
    }
#pragma unroll
    for (int k = 0; k < 4; k++) {
        if (ed[k] >= 0) {
            atomicAdd(&hist_d[ed[k] >> 8], 1);
            atomicAdd(&hist_s[es[k] >> 8], 1);
        }
    }
    __syncthreads();
    // fused exclusive scans of hist_d/hist_s (NB=391) via wave shfl (3 barriers)
    int hvd = (t < NB) ? hist_d[t] : 0;
    int hvs = (t < NB) ? hist_s[t] : 0;
    int vd = hvd, vs = hvs;
#pragma unroll
    for (int off = 1; off < 64; off <<= 1) {
        int ud = __shfl_up(vd, off, 64);
        int us = __shfl_up(vs, off, 64);
        if (lane >= off) { vd += ud; vs += us; }
    }
    if (lane == 63) { woffd[w] = vd; woffs[w] = vs; }
    __syncthreads();
    if (t < 64) {                   // wave 0 scans the 16 wave totals
        int sd = (t < 16) ? woffd[t] : 0;
        int ss = (t < 16) ? woffs[t] : 0;
        int od = sd, os = ss;
#pragma unroll
        for (int off = 1; off < 16; off <<= 1) {
            int ud = __shfl_up(sd, off, 64);
            int us = __shfl_up(ss, off, 64);
            if (lane >= off) { sd += ud; ss += us; }
        }
        if (t < 16) { woffd[t] = sd - od; woffs[t] = ss - os; }
    }
    __syncthreads();
    if (t < NB) {
        lbase_d[t] = vd + woffd[w] - hvd;
        lbase_s[t] = vs + woffs[w] - hvs;
    }
    // reserve global space per bucket
    for (int i = t; i < NB; i += 1024) {
        int c = hist_d[i];
        gbase_d[i] = i * CAPB + (c ? atomicAdd(&g_cur_d[i], c) : 0);
        c = hist_s[i];
        gbase_s[i] = i * CAPB + (c ? atomicAdd(&g_cur_s[i], c) : 0);
    }
    __syncthreads();
    // scatter into LDS stage, grouped by bucket (4-deep serial chain)
#pragma unroll
    for (int k = 0; k < 4; k++) {
        if (ed[k] >= 0) {
            int d = ed[k], s = es[k];
            int bd = d >> 8;
            int r = atomicAdd(&cur_d[bd], 1);
            int pos = lbase_d[bd] + r;
            stage[pos] = (long)(unsigned int)(s | ((d & 255) << 20)) |
                         ((long)__float_as_int(wv[k]) << 32);
            dbuck[pos] = (unsigned short)bd;
            int bs = s >> 8;
            int rs = atomicAdd(&cur_s[bs], 1);
            int ps = lbase_s[bs] + rs;
            sstage[ps] = (unsigned char)(s & 255);
            sbuck[ps] = (unsigned short)bs;
        }
    }
    __syncthreads();
    // stream out: consecutive slots in a bucket -> consecutive global addrs
    long* packl = (long*)pack_part;
    for (int i = t; i < total; i += 1024) {
        int b = dbuck[i];
        packl[(size_t)gbase_d[b] + (i - lbase_d[b])] = stage[i];
    }
    for (int i = t; i < total; i += 1024) {
        int b = sbuck[i];
        src_part[(size_t)gbase_s[b] + (i - lbase_s[b])] = sstage[i];
    }
}

// --- per bucket (1024 threads): dst CSR (hist + wave-0 scan + scatter in LDS)
//     + both norms + fused transform1. pack entries register-cached (pk[4]). ---
__global__ __launch_bounds__(1024) void csr_kernel(
                           const int2* __restrict__ pack_part,
                           const unsigned char* __restrict__ src_part,
                           const int* __restrict__ g_cur_d, const int* __restrict__ g_cur_s,
                           const float* __restrict__ feat, const float* __restrict__ W1,
                           int2* __restrict__ csr, int2* __restrict__ rs_cnt,
                           float* __restrict__ norm_src, float* __restrict__ norm_dst,
                           __half* __restrict__ h1, int n) {
    __shared__ int cnt[256];
    __shared__ int rowx[256];
    __shared__ int cur[256];
    __shared__ int cnt_s[256];
    __shared__ float nsrc[256];
    __shared__ float sW1[1024];
    extern __shared__ int2 stage[];  // CAPB entries (44 KB), reused as fp32 tile later
    int t = threadIdx.x, b = blockIdx.x;
    if (t < 256) { cnt[t] = 0; cur[t] = 0; cnt_s[t] = 0; }
    sW1[t] = W1[t];
    __syncthreads();
    int count = g_cur_d[b]; if (count > CAPB) count = CAPB;
    int count_s = g_cur_s[b]; if (count_s > CAPB) count_s = CAPB;
    const int2* p = pack_part + (size_t)b * CAPB;
    const unsigned char* sp = src_part + (size_t)b * CAPB;
    int2 pk[4];
#pragma unroll
    for (int u = 0; u < 4; u++) {
        int e = t + u * 1024;
        if (e < count) { pk[u] = p[e]; atomicAdd(&cnt[pk[u].x >> 20], 1); }
    }
    for (int e = t + 4096; e < count; e += 1024)    // rare tail past 4096
        atomicAdd(&cnt[p[e].x >> 20], 1);
    for (int e = t; e < count_s; e += 1024) atomicAdd(&cnt_s[sp[e]], 1);
    __syncthreads();
    if (t < 256) {
        int node = b * 256 + t;
        if (node < n) {
            int cs = cnt_s[t];
            float ns = rsqrtf((float)(cs > 1 ? cs : 1));
            nsrc[t] = ns;
            norm_src[node] = ns;
        } else nsrc[t] = 0.0f;
    }
    // wave 0: exclusive scan of cnt[256], 4 items/lane + shfl scan (1 barrier)
    if (t < 64) {
        int c0 = cnt[t * 4], c1 = cnt[t * 4 + 1], c2 = cnt[t * 4 + 2], c3 = cnt[t * 4 + 3];
        int tot = c0 + c1 + c2 + c3;
        int incl = tot;
#pragma unroll
        for (int off = 1; off < 64; off <<= 1) {
            int u = __shfl_up(incl, off, 64);
            if (t >= off) incl += u;
        }
        int excl = incl - tot;
        rowx[t * 4]     = excl;
        rowx[t * 4 + 1] = excl + c0;
        rowx[t * 4 + 2] = excl + c0 + c1;
        rowx[t * 4 + 3] = excl + c0 + c1 + c2;
    }
    __syncthreads();
    if (t < 256) {
        int node = b * 256 + t;
        if (node < n) {
            rs_cnt[node] = make_int2(b * CAPB + rowx[t], cnt[t]);
            norm_dst[node] = rsqrtf((float)(cnt[t] > 1 ? cnt[t] : 1));
        }
    }
    __syncthreads();
#pragma unroll
    for (int u = 0; u < 4; u++) {
        int e = t + u * 1024;
        if (e < count) {
            int2 v = pk[u];
            int dl = v.x >> 20;
            int r = atomicAdd(&cur[dl], 1);
            stage[rowx[dl] + r] = make_int2(v.x & 0x1FFFF, v.y);
        }
    }
    for (int e = t + 4096; e < count; e += 1024) {
        int2 v = p[e];
        int dl = v.x >> 20;
        int r = atomicAdd(&cur[dl], 1);
        stage[rowx[dl] + r] = make_int2(v.x & 0x1FFFF, v.y);
    }
    __syncthreads();
    int2* outp = csr + (size_t)b * CAPB;
    for (int e = t; e < count; e += 1024) outp[e] = stage[e];
    __syncthreads();
    // fused transform1: reuse stage as float tile sF[256][32] (32 KB)
    float* sF = (float*)stage;
    int node0 = b * 256;
    int lim = n - node0; if (lim > 256) lim = 256; if (lim < 0) lim = 0;
    for (int o = t; o < lim * 32; o += 1024) {
        int i = o >> 5, k = o & 31;
        sF[o] = feat[(size_t)(node0 + i) * 32 + k] * nsrc[i];
    }
    __syncthreads();
    for (int o = t; o < lim * 32; o += 1024) {
        int i = o >> 5, col = o & 31;
        float acc = 0.0f;
#pragma unroll
        for (int k = 0; k < 32; k++) acc += sF[i * 32 + k] * sW1[k * 32 + col];
        h1[(size_t)(node0 + i) * 32 + col] = __float2half(acc);
    }
}

// --- gather1 + fused transform2: 16 nodes per wave (4 lanes each, lane owns
//     8 dims via one float4 = 4xhalf2 load) -> 64 edge-rows in flight/wave. ---
__global__ void gather1_fused_kernel(const __half* __restrict__ h1, const int2* __restrict__ csr,
                                     const int2* __restrict__ rs_cnt,
                                     const float* __restrict__ norm_src, const float* __restrict__ norm_dst,
                                     const float* __restrict__ W2, const float* __restrict__ b1,
                                     __half* __restrict__ h2, int n) {
    __shared__ float sW2[32 * 16];
    __shared__ float sB1[32];
    __shared__ float sX[4][16][33];
    int t = threadIdx.x;
    for (int i = t; i < 512; i += 256) sW2[i] = W2[i];
    if (t < 32) sB1[t] = b1[t];
    __syncthreads();
    int w = t >> 6, lane = t & 63;
    int q = lane >> 2;      // sub-node within wave (0..15)
    int dq = lane & 3;      // float4 index (halves 8dq..8dq+7)
    int node = (blockIdx.x * 4 + w) * 16 + q;
    bool valid = node < n;
    int2 rc = valid ? rs_cnt[node] : make_int2(0, 0);
    long base = rc.x;
    int c = rc.y;
    const f32x4* tv = (const f32x4*)h1;     // 4 float4 (32 halves) per row
    const long* csrl = (const long*)csr;
    float a00=0,a01=0,a02=0,a03=0,a04=0,a05=0,a06=0,a07=0;
    float a10=0,a11=0,a12=0,a13=0,a14=0,a15=0,a16=0,a17=0;
    float a20=0,a21=0,a22=0,a23=0,a24=0,a25=0,a26=0,a27=0;
    float a30=0,a31=0,a32=0,a33=0,a34=0,a35=0,a36=0,a37=0;
    int j = 0;
    for (; j + 3 < c; j += 4) {
        long q0 = nt_load_i64(csrl + base + j);
        long q1 = nt_load_i64(csrl + base + j + 1);
        long q2 = nt_load_i64(csrl + base + j + 2);
        long q3 = nt_load_i64(csrl + base + j + 3);
        f32x4 r0 = tv[(size_t)((int)q0 & 0xFFFFF) * 4 + dq];
        f32x4 r1 = tv[(size_t)((int)q1 & 0xFFFFF) * 4 + dq];
        f32x4 r2 = tv[(size_t)((int)q2 & 0xFFFFF) * 4 + dq];
        f32x4 r3 = tv[(size_t)((int)q3 & 0xFFFFF) * 4 + dq];
        float w0 = __int_as_float((int)(q0 >> 32)), w1 = __int_as_float((int)(q1 >> 32));
        float w2 = __int_as_float((int)(q2 >> 32)), w3 = __int_as_float((int)(q3 >> 32));
        const __half2* p0 = (const __half2*)&r0;
        const __half2* p1 = (const __half2*)&r1;
        const __half2* p2 = (const __half2*)&r2;
        const __half2* p3 = (const __half2*)&r3;
        float2 f;
        f = __half22float2(p0[0]); a00 += f.x * w0; a01 += f.y * w0;
        f = __half22float2(p0[1]); a02 += f.x * w0; a03 += f.y * w0;
        f = __half22float2(p0[2]); a04 += f.x * w0; a05 += f.y * w0;
        f = __half22float2(p0[3]); a06 += f.x * w0; a07 += f.y * w0;
        f = __half22float2(p1[0]); a10 += f.x * w1; a11 += f.y * w1;
        f = __half22float2(p1[1]); a12 += f.x * w1; a13 += f.y * w1;
        f = __half22float2(p1[2]); a14 += f.x * w1; a15 += f.y * w1;
        f = __half22float2(p1[3]); a16 += f.x * w1; a17 += f.y * w1;
        f = __half22float2(p2[0]); a20 += f.x * w2; a21 += f.y * w2;
        f = __half22float2(p2[1]); a22 += f.x * w2; a23 += f.y * w2;
        f = __half22float2(p2[2]); a24 += f.x * w2; a25 += f.y * w2;
        f = __half22float2(p2[3]); a26 += f.x * w2; a27 += f.y * w2;
        f = __half22float2(p3[0]); a30 += f.x * w3; a31 += f.y * w3;
        f = __half22float2(p3[1]); a32 += f.x * w3; a33 += f.y * w3;
        f = __half22float2(p3[2]); a34 += f.x * w3; a35 += f.y * w3;
        f = __half22float2(p3[3]); a36 += f.x * w3; a37 += f.y * w3;
    }
    for (; j < c; j++) {
        long qq = nt_load_i64(csrl + base + j);
        f32x4 r = tv[(size_t)((int)qq & 0xFFFFF) * 4 + dq];
        float ww = __int_as_float((int)(qq >> 32));
        const __half2* pp = (const __half2*)&r;
        float2 f;
        f = __half22float2(pp[0]); a00 += f.x * ww; a01 += f.y * ww;
        f = __half22float2(pp[1]); a02 += f.x * ww; a03 += f.y * ww;
        f = __half22float2(pp[2]); a04 += f.x * ww; a05 += f.y * ww;
        f = __half22float2(pp[3]); a06 += f.x * ww; a07 += f.y * ww;
    }
    float s0 = (a00 + a10) + (a20 + a30);
    float s1 = (a01 + a11) + (a21 + a31);
    float s2 = (a02 + a12) + (a22 + a32);
    float s3 = (a03 + a13) + (a23 + a33);
    float s4 = (a04 + a14) + (a24 + a34);
    float s5 = (a05 + a15) + (a25 + a35);
    float s6 = (a06 + a16) + (a26 + a36);
    float s7 = (a07 + a17) + (a27 + a37);
    if (valid) {
        float nd = norm_dst[node], ns = norm_src[node];
        int d0 = 8 * dq;
        sX[w][q][d0]     = fmaxf(s0 * nd + sB1[d0],     0.0f) * ns;
        sX[w][q][d0 + 1] = fmaxf(s1 * nd + sB1[d0 + 1], 0.0f) * ns;
        sX[w][q][d0 + 2] = fmaxf(s2 * nd + sB1[d0 + 2], 0.0f) * ns;
        sX[w][q][d0 + 3] = fmaxf(s3 * nd + sB1[d0 + 3], 0.0f) * ns;
        sX[w][q][d0 + 4] = fmaxf(s4 * nd + sB1[d0 + 4], 0.0f) * ns;
        sX[w][q][d0 + 5] = fmaxf(s5 * nd + sB1[d0 + 5], 0.0f) * ns;
        sX[w][q][d0 + 6] = fmaxf(s6 * nd + sB1[d0 + 6], 0.0f) * ns;
        sX[w][q][d0 + 7] = fmaxf(s7 * nd + sB1[d0 + 7], 0.0f) * ns;
    }
    // wave-synchronous LDS use (same wave wrote sX[w][q]); lane computes 4 cols
    if (valid) {
        float o0 = 0.0f, o1 = 0.0f, o2 = 0.0f, o3 = 0.0f;
        int c0 = 4 * dq;
#pragma unroll
        for (int k = 0; k < 32; k++) {
            float x = sX[w][q][k];
            o0 += x * sW2[k * 16 + c0];
            o1 += x * sW2[k * 16 + c0 + 1];
            o2 += x * sW2[k * 16 + c0 + 2];
            o3 += x * sW2[k * 16 + c0 + 3];
        }
        __half2 lo = __floats2half2_rn(o0, o1);
        __half2 hi = __floats2half2_rn(o2, o3);
        float2 st;
        st.x = __uint_as_float(*(unsigned int*)&lo);
        st.y = __uint_as_float(*(unsigned int*)&hi);
        ((float2*)h2)[(size_t)node * 4 + dq] = st;
    }
}

// --- gather2 + fused epilogue: 32 nodes per wave (2 lanes each, lane owns
//     8 dims via one float4 load) -> 128 edge-rows in flight/wave (2x r11),
//     2 requests/row. Epilogue: two float4 stores per lane. ---
__global__ void gather2_kernel(const __half* __restrict__ h2, const int2* __restrict__ csr,
                               const int2* __restrict__ rs_cnt,
                               const float* __restrict__ norm_dst, const float* __restrict__ b2,
                               float* __restrict__ out, int n) {
    int t = threadIdx.x;
    int w = t >> 6, lane = t & 63;
    int q = lane >> 1;     // sub-node within wave (0..31)
    int dq = lane & 1;     // float4 index (halves 8dq..8dq+7)
    int node = (blockIdx.x * 4 + w) * 32 + q;
    bool valid = node < n;
    int2 rc = valid ? rs_cnt[node] : make_int2(0, 0);
    long base = rc.x;
    int c = rc.y;
    const f32x4* tv = (const f32x4*)h2;     // 2 float4 (16 halves) per row
    const long* csrl = (const long*)csr;
    float a00=0,a01=0,a02=0,a03=0,a04=0,a05=0,a06=0,a07=0;
    float a10=0,a11=0,a12=0,a13=0,a14=0,a15=0,a16=0,a17=0;
    float a20=0,a21=0,a22=0,a23=0,a24=0,a25=0,a26=0,a27=0;
    float a30=0,a31=0,a32=0,a33=0,a34=0,a35=0,a36=0,a37=0;
    int j = 0;
    for (; j + 3 < c; j += 4) {
        long q0 = nt_load_i64(csrl + base + j);
        long q1 = nt_load_i64(csrl + base + j + 1);
        long q2 = nt_load_i64(csrl + base + j + 2);
        long q3 = nt_load_i64(csrl + base + j + 3);
        f32x4 r0 = tv[(size_t)((int)q0 & 0xFFFFF) * 2 + dq];
        f32x4 r1 = tv[(size_t)((int)q1 & 0xFFFFF) * 2 + dq];
        f32x4 r2 = tv[(size_t)((int)q2 & 0xFFFFF) * 2 + dq];
        f32x4 r3 = tv[(size_t)((int)q3 & 0xFFFFF) * 2 + dq];
        float w0 = __int_as_float((int)(q0 >> 32)), w1 = __int_as_float((int)(q1 >> 32));
        float w2 = __int_as_float((int)(q2 >> 32)), w3 = __int_as_float((int)(q3 >> 32));
        const __half2* p0 = (const __half2*)&r0;
        const __half2* p1 = (const __half2*)&r1;
        const __half2* p2 = (const __half2*)&r2;
        const __half2* p3 = (const __half2*)&r3;
        float2 f;
        f = __half22float2(p0[0]); a00 += f.x * w0; a01 += f.y * w0;
        f = __half22float2(p0[1]); a02 += f.x * w0; a03 += f.y * w0;
        f = __half22float2(p0[2]); a04 += f.x * w0; a05 += f.y * w0;
        f = __half22float2(p0[3]); a06 += f.x * w0; a07 += f.y * w0;
        f = __half22float2(p1[0]); a10 += f.x * w1; a11 += f.y * w1;
        f = __half22float2(p1[1]); a12 += f.x * w1; a13 += f.y * w1;
        f = __half22float2(p1[2]); a14 += f.x * w1; a15 += f.y * w1;
        f = __half22float2(p1[3]); a16 += f.x * w1; a17 += f.y * w1;
        f = __half22float2(p2[0]); a20 += f.x * w2; a21 += f.y * w2;
        f = __half22float2(p2[1]); a22 += f.x * w2; a23 += f.y * w2;
        f = __half22float2(p2[2]); a24 += f.x * w2; a25 += f.y * w2;
        f = __half22float2(p2[3]); a26 += f.x * w2; a27 += f.y * w2;
        f = __half22float2(p3[0]); a30 += f.x * w3; a31 += f.y * w3;
        f = __half22float2(p3[1]); a32 += f.x * w3; a33 += f.y * w3;
        f = __half22float2(p3[2]); a34 += f.x * w3; a35 += f.y * w3;
        f = __half22float2(p3[3]); a36 += f.x * w3; a37 += f.y * w3;
    }
    for (; j < c; j++) {
        long qq = nt_load_i64(csrl + base + j);
        f32x4 r = tv[(size_t)((int)qq & 0xFFFFF) * 2 + dq];
        float ww = __int_as_float((int)(qq >> 32));
        const __half2* pp = (const __half2*)&r;
        float2 f;
        f = __half22float2(pp[0]); a00 += f.x * ww; a01 += f.y * ww;
        f = __half22float2(pp[1]); a02 += f.x * ww; a03 += f.y * ww;
        f = __half22float2(pp[2]); a04 += f.x * ww; a05 += f.y * ww;
        f = __half22float2(pp[3]); a06 += f.x * ww; a07 += f.y * ww;
    }
    if (valid) {
        float nd = norm_dst[node];
        int d0 = 8 * dq;
        float4 o0v, o1v;
        o0v.x = ((a00 + a10) + (a20 + a30)) * nd + b2[d0];
        o0v.y = ((a01 + a11) + (a21 + a31)) * nd + b2[d0 + 1];
        o0v.z = ((a02 + a12) + (a22 + a32)) * nd + b2[d0 + 2];
        o0v.w = ((a03 + a13) + (a23 + a33)) * nd + b2[d0 + 3];
        o1v.x = ((a04 + a14) + (a24 + a34)) * nd + b2[d0 + 4];
        o1v.y = ((a05 + a15) + (a25 + a35)) * nd + b2[d0 + 5];
        o1v.z = ((a06 + a16) + (a26 + a36)) * nd + b2[d0 + 6];
        o1v.w = ((a07 + a17) + (a27 + a37)) * nd + b2[d0 + 7];
        ((float4*)out)[(size_t)node * 4 + 2 * dq]     = o0v;
        ((float4*)out)[(size_t)node * 4 + 2 * dq + 1] = o1v;
    }
}

extern "C" void kernel_launch(void* const* d_in, const int* in_sizes, int n_in,
                              void* d_out, int out_size, void* d_ws, size_t ws_size,
                              hipStream_t stream) {
    const float* feat = (const float*)d_in[0];
    const int*   src  = (const int*)d_in[1];
    const int*   dst  = (const int*)d_in[2];
    const float* ew   = (const float*)d_in[3];
    const float* W1   = (const float*)d_in[4];
    const float* b1   = (const float*)d_in[5];
    const float* W2   = (const float*)d_in[6];
    const float* b2   = (const float*)d_in[7];
    float* out = (float*)d_out;

    const int n = in_sizes[0] / 32;  // 100000
    const int m = in_sizes[1];       // 1600000

    // ws: pack_part[NB*CAPB int2] | csr[NB*CAPB int2] | h1 half[32n] | h2 half[16n] |
    //     norm_src[n] | norm_dst[n] | rs_cnt int2[n] | g_cur_d[NB] | g_cur_s[NB] |
    //     src_part uchar[NB*CAPB]
    char* wsb = (char*)d_ws;
    int2*   pack_part = (int2*)wsb;
    int2*   csr       = pack_part + (size_t)NB * CAPB;
    __half* h1        = (__half*)(csr + (size_t)NB * CAPB);
    __half* h2        = h1 + 32 * (size_t)n;
    float*  norm_src  = (float*)(h2 + 16 * (size_t)n);
    float*  norm_dst  = norm_src + n;
    int2*   rs_cnt    = (int2*)(norm_dst + n);
    int*    g_cur_d   = (int*)(rs_cnt + n);
    int*    g_cur_s   = g_cur_d + NB;
    unsigned char* src_part = (unsigned char*)(g_cur_s + NB);

    hipMemsetAsync(g_cur_d, 0, 2 * NB * sizeof(int), stream);

    partition_kernel<<<(m + EPB - 1) / EPB, 1024, 0, stream>>>(src, dst, ew, g_cur_d, g_cur_s,
                                                               pack_part, src_part, m);
    csr_kernel<<<NB, 1024, CAPB * sizeof(int2), stream>>>(pack_part, src_part, g_cur_d, g_cur_s,
                                                          feat, W1, csr, rs_cnt,
                                                          norm_src, norm_dst, h1, n);
    gather1_fused_kernel<<<(n + 63) / 64, 256, 0, stream>>>(h1, csr, rs_cnt,
                                                            norm_src, norm_dst, W2, b1, h2, n);
    gather2_kernel<<<(n + 127) / 128, 256, 0, stream>>>(h2, csr, rs_cnt, norm_dst, b2, out, n);
}